// Round 6
// baseline (293.314 us; speedup 1.0000x reference)
//
#include <hip/hip_runtime.h>

#define S 2048
#define D 128
#define BATCH 8

typedef _Float16 half8 __attribute__((ext_vector_type(8)));
typedef _Float16 half4_t __attribute__((ext_vector_type(4)));
typedef float f4 __attribute__((ext_vector_type(4)));

__device__ __forceinline__ half8 cvt8(f4 a, f4 b) {
    half8 h;
    h[0] = (_Float16)a[0]; h[1] = (_Float16)a[1];
    h[2] = (_Float16)a[2]; h[3] = (_Float16)a[3];
    h[4] = (_Float16)b[0]; h[5] = (_Float16)b[1];
    h[6] = (_Float16)b[2]; h[7] = (_Float16)b[7 - 7 + 3];
    h[4] = (_Float16)b[0]; h[5] = (_Float16)b[1];
    h[6] = (_Float16)b[2]; h[7] = (_Float16)b[3];
    return h;
}

// ---- fused prep: K cast fp16, V transpose -> vt[b][d][t] fp16, V col-sums ----
// 512 blocks (32-row chunks) = 2 blocks/CU; b = bid & 7 keeps batch->XCD affinity.
__global__ __launch_bounds__(256) void k_prep(const float* __restrict__ kin,
                                              const float* __restrict__ v,
                                              _Float16* __restrict__ kh,
                                              _Float16* __restrict__ vt,
                                              float* __restrict__ sums) {
    int bid = blockIdx.x;
    int b = bid & 7, c = bid >> 3, tid = threadIdx.x;   // c: 0..63, 32 rows each
    size_t off = ((size_t)b * S + c * 32) * D;
    #pragma unroll
    for (int p = 0; p < 2; ++p) {
        size_t i = (size_t)p * 2048 + tid * 8;
        f4 a = *(const f4*)(kin + off + i);
        f4 bb = *(const f4*)(kin + off + i + 4);
        *(half8*)(kh + off + i) = cvt8(a, bb);
    }
    __shared__ float tile[32 * 132];
    __shared__ f4 sred[256][2];
    f4 a0 = {0.f, 0.f, 0.f, 0.f}, a1 = {0.f, 0.f, 0.f, 0.f};
    int d0 = (tid & 15) * 8;
    #pragma unroll
    for (int p = 0; p < 2; ++p) {
        int t = p * 16 + (tid >> 4);
        f4 x = *(const f4*)(v + off + (size_t)t * D + d0);
        f4 y = *(const f4*)(v + off + (size_t)t * D + d0 + 4);
        a0 += x; a1 += y;
        *(f4*)&tile[t * 132 + d0] = x;
        *(f4*)&tile[t * 132 + d0 + 4] = y;
    }
    sred[tid][0] = a0; sred[tid][1] = a1;
    __syncthreads();
    if (tid < 16) {
        f4 s0 = sred[tid][0], s1 = sred[tid][1];
        for (int g = 1; g < 16; ++g) { s0 += sred[g * 16 + tid][0]; s1 += sred[g * 16 + tid][1]; }
        float* dst = sums + b * D + tid * 8;
        #pragma unroll
        for (int i = 0; i < 4; ++i) { atomicAdd(dst + i, s0[i]); atomicAdd(dst + 4 + i, s1[i]); }
    }
    int u = tid & 3, dd = tid >> 2;                    // u: 8 t's each, dd: 0..63
    #pragma unroll
    for (int pass = 0; pass < 2; ++pass) {
        int d = pass * 64 + dd;
        half8 h;
        #pragma unroll
        for (int i = 0; i < 8; ++i) h[i] = (_Float16)tile[(u * 8 + i) * 132 + d];
        *(half8*)(vt + ((size_t)(b * D + d)) * S + c * 32 + u * 8) = h;
    }
}

// ---- main: flash attention, BARRIER-FREE main loop. One 1024-thread block
// (16 waves = 4 key-groups x 4 row-waves) owns one (b, mg) 64-row group.
// K/V for a batch is 2.1 MB fp16 = L2-resident (XCD-pinned via b = bid & 7),
// so each wave free-runs its own key-quarter reading K/V fragments DIRECTLY
// from L2 — no LDS staging, no __syncthreads in the loop, register
// double-buffer of the next tile's fragments. 4 independent waves/SIMD give
// phase diversity; one barrier total at the LDS-atomic combine epilogue.
__global__ __launch_bounds__(1024, 4) void k_attn(
    const float* __restrict__ q, const _Float16* __restrict__ kh,
    const _Float16* __restrict__ vt, const int* __restrict__ el,
    const float* __restrict__ sums, float* __restrict__ out) {
    int bid = blockIdx.x;
    int b = bid & 7, mg = bid >> 3;
    int Lb = el[b], m0 = mg * 64;
    int tid = threadIdx.x;
    const float inv_s = 1.0f / (float)S;

    if (m0 >= Lb) {
        // whole group invalid -> out = colmean(V) for every row
        int r = tid >> 4, d0 = (tid & 15) * 8;
        float* orow = out + ((size_t)b * S + m0 + r) * D + d0;
        *(f4*)(orow) = *(const f4*)(sums + b * D + d0) * inv_s;
        *(f4*)(orow + 4) = *(const f4*)(sums + b * D + d0 + 4) * inv_s;
        return;
    }
    int nkt = (Lb + 63) >> 6;

    int lane = tid & 63, w = tid >> 6;
    int g = w >> 2, wl = w & 3;        // key-subtile group, row-wave
    int col = lane & 15, quad = lane >> 4;

    __shared__ float cmb[64 * 132];    // combine buffer (stride 132: 2-way = free)
    __shared__ float psb[64];

    // Q frags (B-operand of the S^T MFMA), fp32 -> fp16 with 1/sqrt(D).
    // The 4 groups load the same rows (L1 hit after first).
    const float scale = 0.0883883476483184f;
    half8 qf[4];
    {
        const float* qb = q + ((size_t)b * S + m0 + wl * 16 + col) * D;
        #pragma unroll
        for (int kc = 0; kc < 4; ++kc) {
            f4 a = *(const f4*)(qb + kc * 32 + quad * 8);
            f4 b2 = *(const f4*)(qb + kc * 32 + quad * 8 + 4);
            a *= scale; b2 *= scale;
            qf[kc] = cvt8(a, b2);
        }
    }

    f4 O[8];
    #pragma unroll
    for (int i = 0; i < 8; ++i) O[i] = (f4){0.f, 0.f, 0.f, 0.f};
    float ps = 0.f;

    // this wave's fragment addresses: keys t0 + col (K) / t0 + quad*4 (V),
    // t0 = kt*64 + g*16
    const _Float16* kp = kh + ((size_t)b * S + g * 16 + col) * D + (quad << 3);
    const _Float16* vp = vt + ((size_t)b * D + col) * S + g * 16 + (quad << 2);

    half8 kf[4];
    half4_t vf[8];
    #pragma unroll
    for (int kc = 0; kc < 4; ++kc) kf[kc] = *(const half8*)(kp + kc * 32);
    #pragma unroll
    for (int dt = 0; dt < 8; ++dt) vf[dt] = *(const half4_t*)(vp + (size_t)dt * 16 * S);

    for (int kt = 0; kt < nkt; ++kt) {
        int t0 = kt * 64 + g * 16;
        bool hasnext = (kt + 1) < nkt;
        half8 kn[4];
        half4_t vn[8];
        if (hasnext) {  // prefetch next tile's fragments (pure register dbuf)
            #pragma unroll
            for (int kc = 0; kc < 4; ++kc)
                kn[kc] = *(const half8*)(kp + (size_t)(kt + 1) * 64 * D + kc * 32);
            #pragma unroll
            for (int dt = 0; dt < 8; ++dt)
                vn[dt] = *(const half4_t*)(vp + (size_t)dt * 16 * S + (kt + 1) * 64);
        }

        // S^T = K Q^T for this group's 16 keys: C[key = g*16+quad*4+r][qrow = col]
        f4 sa = {0.f, 0.f, 0.f, 0.f};
        __builtin_amdgcn_s_setprio(1);
        #pragma unroll
        for (int kc = 0; kc < 4; ++kc)
            sa = __builtin_amdgcn_mfma_f32_16x16x32_f16(kf[kc], qf[kc], sa, 0, 0, 0);
        __builtin_amdgcn_s_setprio(0);
        // exp with key-validity mask; P = A-frag of 16x16x16 (k=quad*4+r)
        int tq = t0 + quad * 4;
        half4_t ph;
        #pragma unroll
        for (int r = 0; r < 4; ++r) {
            float e = (tq + r < Lb) ? __expf(fminf(sa[r], 10.0f)) : 0.f;
            ps += e;
            ph[r] = (_Float16)e;
        }
        // O += P V for this 16-key group
        __builtin_amdgcn_s_setprio(1);
        #pragma unroll
        for (int dt = 0; dt < 8; ++dt)
            O[dt] = __builtin_amdgcn_mfma_f32_16x16x16f16(ph, vf[dt], O[dt], 0, 0, 0);
        __builtin_amdgcn_s_setprio(0);

        if (hasnext) {
            #pragma unroll
            for (int kc = 0; kc < 4; ++kc) kf[kc] = kn[kc];
            #pragma unroll
            for (int dt = 0; dt < 8; ++dt) vf[dt] = vn[dt];
        }
    }

    // ---- epilogue: 4-way combine in LDS, then normalize + write ----
    ps += __shfl_xor(ps, 16, 64);      // row-sum over this group's keys
    ps += __shfl_xor(ps, 32, 64);

    if (g == 0) {                      // group 0 seeds the combine buffer
        #pragma unroll
        for (int dt = 0; dt < 8; ++dt)
            #pragma unroll
            for (int r = 0; r < 4; ++r)
                cmb[(wl * 16 + quad * 4 + r) * 132 + dt * 16 + col] = O[dt][r];
        if (quad == 0) psb[wl * 16 + col] = ps;
    }
    __syncthreads();
    if (g != 0) {                      // groups 1-3 accumulate (LDS atomics)
        #pragma unroll
        for (int dt = 0; dt < 8; ++dt)
            #pragma unroll
            for (int r = 0; r < 4; ++r)
                atomicAdd(&cmb[(wl * 16 + quad * 4 + r) * 132 + dt * 16 + col], O[dt][r]);
        if (quad == 0) atomicAdd(&psb[wl * 16 + col], ps);
    }
    __syncthreads();
    if (g == 0) {                      // group 0 normalizes + writes output
        float pst = psb[wl * 16 + col];          // total row-sum for qrow = col
        float l4[4];
        #pragma unroll
        for (int r = 0; r < 4; ++r) l4[r] = __shfl(pst, quad * 4 + r, 64);

        bool tail = (m0 + 64 > Lb);
        float smv[8] = {};
        if (tail) {
            #pragma unroll
            for (int dt = 0; dt < 8; ++dt) smv[dt] = sums[b * D + dt * 16 + col] * inv_s;
        }
        #pragma unroll
        for (int r = 0; r < 4; ++r) {
            int row = m0 + wl * 16 + quad * 4 + r;
            float inv = 1.0f / l4[r];
            float* orow = out + ((size_t)b * S + row) * D;
            #pragma unroll
            for (int dt = 0; dt < 8; ++dt) {
                float val = (row < Lb)
                    ? cmb[(wl * 16 + quad * 4 + r) * 132 + dt * 16 + col] * inv
                    : smv[dt];
                orow[dt * 16 + col] = val;
            }
        }
    }
}

extern "C" void kernel_launch(void* const* d_in, const int* in_sizes, int n_in,
                              void* d_out, int out_size, void* d_ws, size_t ws_size,
                              hipStream_t stream) {
    const float* q = (const float*)d_in[0];
    const float* k = (const float*)d_in[1];
    const float* v = (const float*)d_in[2];
    const int* el = (const int*)d_in[3];
    float* out = (float*)d_out;

    const size_t SZ_SUMS = 4096;
    const size_t SZ_HALF = (size_t)BATCH * D * S * 2;     // 4.19 MB each
    float* sums = (float*)d_ws;
    _Float16* kh = (_Float16*)((char*)d_ws + SZ_SUMS);
    _Float16* vt = (_Float16*)((char*)d_ws + SZ_SUMS + SZ_HALF);

    hipMemsetAsync(d_ws, 0, SZ_SUMS, stream);
    k_prep<<<dim3(512), 256, 0, stream>>>(k, v, kh, vt, sums);
    k_attn<<<dim3(256), 1024, 0, stream>>>(q, kh, vt, el, sums, out);
}

// Round 7
// 125.748 us; speedup vs baseline: 2.3325x; 2.3325x over previous
//
#include <hip/hip_runtime.h>

#define S 2048
#define D 128
#define BATCH 8
#define KSTR 136   // K LDS row stride (halves)
#define VSTR 72    // V^T LDS row stride (halves)

typedef _Float16 half8 __attribute__((ext_vector_type(8)));
typedef _Float16 half4_t __attribute__((ext_vector_type(4)));
typedef float f4 __attribute__((ext_vector_type(4)));

__device__ __forceinline__ half8 cvt8(f4 a, f4 b) {
    half8 h;
    h[0] = (_Float16)a[0]; h[1] = (_Float16)a[1];
    h[2] = (_Float16)a[2]; h[3] = (_Float16)a[3];
    h[4] = (_Float16)b[0]; h[5] = (_Float16)b[1];
    h[6] = (_Float16)b[2]; h[7] = (_Float16)b[3];
    return h;
}

// ---- fused prep: K cast fp16, V transpose -> vt[b][d][t] fp16, and per-chunk
// V column-sum partials (NO atomics, NO memset needed). 512 blocks, 32 rows each.
__global__ __launch_bounds__(256) void k_prep(const float* __restrict__ kin,
                                              const float* __restrict__ v,
                                              _Float16* __restrict__ kh,
                                              _Float16* __restrict__ vt,
                                              float* __restrict__ part) {
    int bid = blockIdx.x;
    int b = bid & 7, c = bid >> 3, tid = threadIdx.x;   // c: 0..63, 32 rows each
    size_t off = ((size_t)b * S + c * 32) * D;
    #pragma unroll
    for (int p = 0; p < 2; ++p) {
        size_t i = (size_t)p * 2048 + tid * 8;
        f4 a = *(const f4*)(kin + off + i);
        f4 bb = *(const f4*)(kin + off + i + 4);
        *(half8*)(kh + off + i) = cvt8(a, bb);
    }
    __shared__ float tile[32 * 132];
    __shared__ f4 sred[256][2];
    f4 a0 = {0.f, 0.f, 0.f, 0.f}, a1 = {0.f, 0.f, 0.f, 0.f};
    int d0 = (tid & 15) * 8;
    #pragma unroll
    for (int p = 0; p < 2; ++p) {
        int t = p * 16 + (tid >> 4);
        f4 x = *(const f4*)(v + off + (size_t)t * D + d0);
        f4 y = *(const f4*)(v + off + (size_t)t * D + d0 + 4);
        a0 += x; a1 += y;
        *(f4*)&tile[t * 132 + d0] = x;
        *(f4*)&tile[t * 132 + d0 + 4] = y;
    }
    sred[tid][0] = a0; sred[tid][1] = a1;
    __syncthreads();
    if (tid < 16) {     // per-chunk partial colsum -> plain stores, no atomics
        f4 s0 = sred[tid][0], s1 = sred[tid][1];
        for (int g = 1; g < 16; ++g) { s0 += sred[g * 16 + tid][0]; s1 += sred[g * 16 + tid][1]; }
        float* dst = part + ((size_t)b * 64 + c) * 128 + tid * 8;
        *(f4*)dst = s0;
        *(f4*)(dst + 4) = s1;
    }
    int u = tid & 3, dd = tid >> 2;                    // u: 8 t's each, dd: 0..63
    #pragma unroll
    for (int pass = 0; pass < 2; ++pass) {
        int d = pass * 64 + dd;
        half8 h;
        #pragma unroll
        for (int i = 0; i < 8; ++i) h[i] = (_Float16)tile[(u * 8 + i) * 132 + d];
        *(half8*)(vt + ((size_t)(b * D + d)) * S + c * 32 + u * 8) = h;
    }
}

// ---- main: flash attention. One 256-thread block (4 waves = 2 row-waves x
// 2 nt-halves) owns a 32-row group. Grid = 512 blocks -> 2+ independent
// blocks/CU (TLP across blocks, the R0 lesson), proven LDS-staged tile +
// register-prefetch loop (fits 128-VGPR cap; measured 64 in this shape),
// intra-block 2-way LDS combine (no fences, no extra kernels). Diagonal
// b = (bid+rg)&7 spreads each batch across XCDs and mixes long/short
// batches in dispatch order for load balance.
__global__ __launch_bounds__(256, 4) void k_attn(
    const float* __restrict__ q, const _Float16* __restrict__ kh,
    const _Float16* __restrict__ vt, const int* __restrict__ el,
    const float* __restrict__ part, float* __restrict__ out) {
    int bid = blockIdx.x;
    int rg = bid >> 3;                 // 0..63 row-group
    int b = (bid + rg) & 7;            // diagonal batch mapping
    int Lb = el[b], m0 = rg * 32;
    int tid = threadIdx.x;
    const float inv_s = 1.0f / (float)S;

    // LDS: staging (Kh 17408B + Vt 18432B) overlaid by combine buffers after loop
    __shared__ __align__(16) char smem[35840];
    _Float16* Kh = (_Float16*)smem;
    _Float16* Vt = (_Float16*)(smem + 17408);
    float* cmb  = (float*)smem;                 // 32 x 132 f32 = 16896 B
    float* psb  = (float*)(smem + 16896);       // 32 f32 = 128 B
    float* vsum = (float*)(smem + 17024);       // 128 f32 = 512 B

    if (m0 >= Lb) {
        // whole group invalid -> out = colmean(V): reduce 64 prep partials
        if (tid < 128) {
            float s = 0.f;
            const float* pp = part + (size_t)b * 64 * 128 + tid;
            #pragma unroll 4
            for (int c = 0; c < 64; ++c) s += pp[c * 128];
            vsum[tid] = s * inv_s;
        }
        __syncthreads();
        int r = tid >> 3, d0 = (tid & 7) * 16;
        float* orow = out + ((size_t)b * S + m0 + r) * D + d0;
        #pragma unroll
        for (int i = 0; i < 4; ++i) *(f4*)(orow + i * 4) = *(const f4*)(vsum + d0 + i * 4);
        return;
    }
    int nkt = (Lb + 63) >> 6;

    int lane = tid & 63, w = tid >> 6;
    int h = w >> 1, wl = w & 1;        // nt-half, row-wave
    int col = lane & 15, quad = lane >> 4;

    // Q frags (B-operand of the S^T MFMA), fp32 -> fp16 with 1/sqrt(D)
    const float scale = 0.0883883476483184f;
    half8 qf[4];
    {
        const float* qb = q + ((size_t)b * S + m0 + wl * 16 + col) * D;
        #pragma unroll
        for (int kc = 0; kc < 4; ++kc) {
            f4 a = *(const f4*)(qb + kc * 32 + quad * 8);
            f4 b2 = *(const f4*)(qb + kc * 32 + quad * 8 + 4);
            a *= scale; b2 *= scale;
            qf[kc] = cvt8(a, b2);
        }
    }

    f4 O[8];
    #pragma unroll
    for (int i = 0; i < 8; ++i) O[i] = (f4){0.f, 0.f, 0.f, 0.f};
    float ps = 0.f;

    int kr = tid >> 4, kc8 = (tid & 15) << 3;   // K stage: 4 rows/thread of 64
    int vr = tid >> 3, vc8 = (tid & 7) << 3;    // V stage: 4 d-rows/thread of 128
    const _Float16* kb_ = kh + (size_t)b * S * D;
    const _Float16* vb_ = vt + (size_t)b * D * S;

    half8 kreg[4], vreg[4];
    {   // stage tile 0
        #pragma unroll
        for (int p = 0; p < 4; ++p)
            kreg[p] = *(const half8*)(kb_ + (size_t)(p * 16 + kr) * D + kc8);
        #pragma unroll
        for (int p = 0; p < 4; ++p)
            vreg[p] = *(const half8*)(vb_ + (size_t)(p * 32 + vr) * S + vc8);
        #pragma unroll
        for (int p = 0; p < 4; ++p)
            *(half8*)&Kh[(p * 16 + kr) * KSTR + kc8] = kreg[p];
        #pragma unroll
        for (int p = 0; p < 4; ++p)
            *(half8*)&Vt[(p * 32 + vr) * VSTR + vc8] = vreg[p];
    }
    __syncthreads();

    for (int kt = 0; kt < nkt; ++kt) {
        int t0 = kt * 64;
        bool hasnext = (kt + 1) < nkt;
        if (hasnext) {  // prefetch next tile into regs, overlaps compute
            int tn = t0 + 64;
            #pragma unroll
            for (int p = 0; p < 4; ++p)
                kreg[p] = *(const half8*)(kb_ + (size_t)(tn + p * 16 + kr) * D + kc8);
            #pragma unroll
            for (int p = 0; p < 4; ++p)
                vreg[p] = *(const half8*)(vb_ + (size_t)(p * 32 + vr) * S + tn + vc8);
        }

        #pragma unroll
        for (int nt2 = 0; nt2 < 2; ++nt2) {
            int nt = h * 2 + nt2;      // this half's key sub-tile
            // S^T = K Q^T: C[key = nt*16 + quad*4 + r][qrow = col]
            f4 sa = {0.f, 0.f, 0.f, 0.f};
            __builtin_amdgcn_s_setprio(1);
            #pragma unroll
            for (int kc = 0; kc < 4; ++kc) {
                half8 kf = *(const half8*)&Kh[(nt * 16 + col) * KSTR + kc * 32 + quad * 8];
                sa = __builtin_amdgcn_mfma_f32_16x16x32_f16(kf, qf[kc], sa, 0, 0, 0);
            }
            __builtin_amdgcn_s_setprio(0);
            // exp with key-validity mask; P = A-frag of 16x16x16 (k=quad*4+r)
            int tq = t0 + nt * 16 + quad * 4;
            half4_t ph;
            #pragma unroll
            for (int r = 0; r < 4; ++r) {
                float e = (tq + r < Lb) ? __expf(fminf(sa[r], 10.0f)) : 0.f;
                ps += e;
                ph[r] = (_Float16)e;
            }
            // O += P V for this 16-key group
            __builtin_amdgcn_s_setprio(1);
            #pragma unroll
            for (int dt = 0; dt < 8; ++dt) {
                half4_t vf = *(const half4_t*)&Vt[(dt * 16 + col) * VSTR + nt * 16 + quad * 4];
                O[dt] = __builtin_amdgcn_mfma_f32_16x16x16f16(ph, vf, O[dt], 0, 0, 0);
            }
            __builtin_amdgcn_s_setprio(0);
        }

        if (hasnext) {
            __syncthreads();
            #pragma unroll
            for (int p = 0; p < 4; ++p)
                *(half8*)&Kh[(p * 16 + kr) * KSTR + kc8] = kreg[p];
            #pragma unroll
            for (int p = 0; p < 4; ++p)
                *(half8*)&Vt[(p * 32 + vr) * VSTR + vc8] = vreg[p];
            __syncthreads();
        }
    }

    // ---- epilogue: 2-way combine in LDS (overlay on staging), then write ----
    __syncthreads();                   // all staging reads done; LDS reusable
    bool tail = (m0 + 32 > Lb);        // block-uniform
    if (tail && tid < 128) {           // colmean for rows >= L in this group
        float s = 0.f;
        const float* pp = part + (size_t)b * 64 * 128 + tid;
        #pragma unroll 4
        for (int c = 0; c < 64; ++c) s += pp[c * 128];
        vsum[tid] = s * inv_s;
    }
    ps += __shfl_xor(ps, 16, 64);      // row-sum over this half's keys
    ps += __shfl_xor(ps, 32, 64);

    if (h == 0) {                      // half 0 seeds the combine buffer
        #pragma unroll
        for (int dt = 0; dt < 8; ++dt)
            #pragma unroll
            for (int r = 0; r < 4; ++r)
                cmb[(wl * 16 + quad * 4 + r) * 132 + dt * 16 + col] = O[dt][r];
        if (quad == 0) psb[wl * 16 + col] = ps;
    }
    __syncthreads();
    if (h == 1) {                      // half 1 accumulates (LDS atomics)
        #pragma unroll
        for (int dt = 0; dt < 8; ++dt)
            #pragma unroll
            for (int r = 0; r < 4; ++r)
                atomicAdd(&cmb[(wl * 16 + quad * 4 + r) * 132 + dt * 16 + col], O[dt][r]);
        if (quad == 0) atomicAdd(&psb[wl * 16 + col], ps);
    }
    __syncthreads();
    if (h == 0) {                      // half 0 normalizes + writes output
        float pst = psb[wl * 16 + col];          // total row-sum for qrow = col
        float l4[4];
        #pragma unroll
        for (int r = 0; r < 4; ++r) l4[r] = __shfl(pst, quad * 4 + r, 64);

        float smv[8] = {};
        if (tail) {
            #pragma unroll
            for (int dt = 0; dt < 8; ++dt) smv[dt] = vsum[dt * 16 + col];
        }
        #pragma unroll
        for (int r = 0; r < 4; ++r) {
            int row = m0 + wl * 16 + quad * 4 + r;
            float inv = 1.0f / l4[r];
            float* orow = out + ((size_t)b * S + row) * D;
            #pragma unroll
            for (int dt = 0; dt < 8; ++dt) {
                float val = (row < Lb)
                    ? cmb[(wl * 16 + quad * 4 + r) * 132 + dt * 16 + col] * inv
                    : smv[dt];
                orow[dt * 16 + col] = val;
            }
        }
    }
}

extern "C" void kernel_launch(void* const* d_in, const int* in_sizes, int n_in,
                              void* d_out, int out_size, void* d_ws, size_t ws_size,
                              hipStream_t stream) {
    const float* q = (const float*)d_in[0];
    const float* k = (const float*)d_in[1];
    const float* v = (const float*)d_in[2];
    const int* el = (const int*)d_in[3];
    float* out = (float*)d_out;

    const size_t SZ_PART = (size_t)BATCH * 64 * 128 * 4;  // 256 KB partial colsums
    const size_t SZ_HALF = (size_t)BATCH * D * S * 2;     // 4.19 MB each
    float* part = (float*)d_ws;
    _Float16* kh = (_Float16*)((char*)d_ws + SZ_PART);
    _Float16* vt = (_Float16*)((char*)d_ws + SZ_PART + SZ_HALF);

    k_prep<<<dim3(512), 256, 0, stream>>>(k, v, kh, vt, part);
    k_attn<<<dim3(512), 256, 0, stream>>>(q, kh, vt, el, part, out);
}